// Round 1
// 198.845 us; speedup vs baseline: 1.0596x; 1.0596x over previous
//
#include <hip/hip_runtime.h>
#include <hip/hip_bf16.h>

typedef __hip_bfloat16 bf16;
typedef float fx4 __attribute__((ext_vector_type(4)));
typedef float f32x4 __attribute__((ext_vector_type(4)));
typedef __bf16 bfx8 __attribute__((ext_vector_type(8)));
typedef unsigned short u16x8 __attribute__((ext_vector_type(8)));

constexpr int T    = 2048;  // sequence length
constexpr int CE   = 1024;  // n_embd
constexpr int QKVC = 3072;  // 3 * n_embd
constexpr int H    = 16;
constexpr int HD   = 64;

// ---------------------------------------------------------------------------
// Dtype sniff (flag=1 -> fp32 bytes; flag=0 -> bf16; rounds 2-12 measured 0).
// ---------------------------------------------------------------------------
__global__ __launch_bounds__(64) void sniff_kernel(const void* __restrict__ x,
                                                   int* __restrict__ hdr) {
  if (threadIdx.x == 0) {
    const unsigned short* p = (const unsigned short*)x;
    int c = 0;
    for (int i = 0; i < 256; ++i) {
      const unsigned e = (p[i] >> 7) & 0xFF;
      if (e >= 137) ++c;
    }
    hdr[0] = (c >= 8) ? 1 : 0;  // flag
  }
}

// ---------------------------------------------------------------------------
// Fused conversion of all 5 inputs (early-out when already bf16).
// THIS ROUND: grid-stride with 2048 blocks (was 6148 one-shot blocks) to cut
// dead-path dispatch overhead when flag=0.
// ---------------------------------------------------------------------------
constexpr int S0 = T * CE / 4;
constexpr int S1 = QKVC * CE / 4;
constexpr int S2 = QKVC / 4;
constexpr int S3 = CE * CE / 4;
constexpr int S4 = CE / 4;
constexpr int STOT = S0 + S1 + S2 + S3 + S4;
constexpr int CONV_BLOCKS = 2048;

__global__ __launch_bounds__(256) void conv_all(const void* __restrict__ in0,
                                                const void* __restrict__ in1,
                                                const void* __restrict__ in2,
                                                const void* __restrict__ in3,
                                                const void* __restrict__ in4,
                                                __bf16* __restrict__ o0,
                                                __bf16* __restrict__ o1,
                                                __bf16* __restrict__ o2,
                                                __bf16* __restrict__ o3,
                                                __bf16* __restrict__ o4,
                                                const int* __restrict__ flag) {
  if (*flag == 0) return;
  for (int i = blockIdx.x * 256 + threadIdx.x; i < STOT; i += CONV_BLOCKS * 256) {
    int t = i;
    const float* src;
    __bf16* dst;
    if (t < S0)                { src = (const float*)in0; dst = o0; }
    else if ((t -= S0) < S1)   { src = (const float*)in1; dst = o1; }
    else if ((t -= S1) < S2)   { src = (const float*)in2; dst = o2; }
    else if ((t -= S2) < S3)   { src = (const float*)in3; dst = o3; }
    else                       { t -= S3; src = (const float*)in4; dst = o4; }
    const fx4 v = ((const fx4*)src)[t];
    __bf16* o = dst + (size_t)t * 4;
    o[0] = (__bf16)v.x; o[1] = (__bf16)v.y; o[2] = (__bf16)v.z; o[3] = (__bf16)v.w;
  }
}

// ---------------------------------------------------------------------------
// MFMA NT GEMM: C = A·B^T + bias. Fragment math + staging + pipelined dbuf
// K-loop HW-verified rounds 5-12. 64x128 tile (wave owns 64 m-rows x 32
// n-cols; acc[4][2]). GEMM1 grid 768 = 3/CU balanced; GEMM2 grid 256.
// OUT_MODE 1: bf16/fp32 store per *flag. OUT_MODE 2: bf16 + q0k0 side-store.
// Unchanged this round.
// ---------------------------------------------------------------------------
template<int N, int K, int OUT_MODE>
__global__ __launch_bounds__(256) void gemm_mfma_nt(const __bf16* __restrict__ Ac,
                                                    const void* __restrict__ Araw,
                                                    const __bf16* __restrict__ Bc,
                                                    const void* __restrict__ Braw,
                                                    const __bf16* __restrict__ biasc,
                                                    const void* __restrict__ biasraw,
                                                    void* __restrict__ Cout,
                                                    float* __restrict__ Cout2,
                                                    const int* __restrict__ flag) {
  const int f = *flag;
  const __bf16* A    = f ? Ac    : (const __bf16*)Araw;
  const __bf16* B    = f ? Bc    : (const __bf16*)Braw;
  const __bf16* bias = f ? biasc : (const __bf16*)biasraw;

  constexpr int LDT = 40;
  constexpr int HALFA = 64 * LDT;
  constexpr int HALFB = 128 * LDT;
  __shared__ __bf16 As[2 * HALFA];
  __shared__ __bf16 Bs[2 * HALFB];
  const int bm = blockIdx.y * 64, bn = blockIdx.x * 128;
  const int tid  = threadIdx.x;
  const int wave = tid >> 6, lane = tid & 63;
  const int wn = wave * 32;
  const int l15 = lane & 15, quad = lane >> 4;
  const int r0 = tid >> 2, kc = (tid & 3) * 8;

  f32x4 acc[4][2];
#pragma unroll
  for (int i = 0; i < 4; ++i)
#pragma unroll
    for (int j = 0; j < 2; ++j) acc[i][j] = (f32x4){0.f, 0.f, 0.f, 0.f};

  // prologue: k0=0 tile
  u16x8 a0 = *(const u16x8*)(A + (size_t)(bm + r0)      * K + kc);
  u16x8 b0 = *(const u16x8*)(B + (size_t)(bn + r0)      * K + kc);
  u16x8 b1 = *(const u16x8*)(B + (size_t)(bn + r0 + 64) * K + kc);

  for (int k0 = 0; k0 < K; k0 += 32) {
    const int sel = (k0 >> 5) & 1;
    const int bufA = sel * HALFA, bufB = sel * HALFB;
    *(u16x8*)&As[bufA + (r0)      * LDT + kc] = a0;
    *(u16x8*)&Bs[bufB + (r0)      * LDT + kc] = b0;
    *(u16x8*)&Bs[bufB + (r0 + 64) * LDT + kc] = b1;

    if (k0 + 32 < K) {  // next tile's loads overlap barrier + compute
      const int kn = k0 + 32 + kc;
      a0 = *(const u16x8*)(A + (size_t)(bm + r0)      * K + kn);
      b0 = *(const u16x8*)(B + (size_t)(bn + r0)      * K + kn);
      b1 = *(const u16x8*)(B + (size_t)(bn + r0 + 64) * K + kn);
    }

    __syncthreads();

    bfx8 af[4], bfr[2];
#pragma unroll
    for (int i = 0; i < 4; ++i)
      af[i]  = *(const bfx8*)&As[bufA + (i * 16 + l15) * LDT + quad * 8];
#pragma unroll
    for (int j = 0; j < 2; ++j)
      bfr[j] = *(const bfx8*)&Bs[bufB + (wn + j * 16 + l15) * LDT + quad * 8];
#pragma unroll
    for (int i = 0; i < 4; ++i)
#pragma unroll
      for (int j = 0; j < 2; ++j)
        acc[i][j] = __builtin_amdgcn_mfma_f32_16x16x32_bf16(af[i], bfr[j], acc[i][j], 0, 0, 0);
  }

#pragma unroll
  for (int i = 0; i < 4; ++i)
#pragma unroll
    for (int j = 0; j < 2; ++j)
#pragma unroll
      for (int r = 0; r < 4; ++r) {
        const int m = bm + i * 16 + quad * 4 + r;
        const int n = bn + wn + j * 16 + l15;
        const float v = acc[i][j][r] + (float)bias[n];
        const size_t idx = (size_t)m * N + n;
        if (OUT_MODE == 2) {
          ((__bf16*)Cout)[idx] = (__bf16)v;
          if (n < 64)                      Cout2[m * 128 + n] = v;
          else if (n >= 1024 && n < 1088)  Cout2[m * 128 + 64 + (n - 1024)] = v;
        } else {
          if (f) ((float*)Cout)[idx] = v;
          else   ((__bf16*)Cout)[idx] = (__bf16)v;
        }
      }
}

// ---------------------------------------------------------------------------
// FF 2-phase chunked scan. THIS ROUND:
//  (a) Triangular block skip: S[r][j] contributes only when r > j, so block
//      (rc, jb) is pure zero-work unless rc >= 8*jb. Skipped part[] entries
//      are exactly 0.0f and skipped FF cells are never read by attn
//      (every FF cell attn touches -- incl. masked diagonal-tile reads --
//      satisfies 256*jb <= 32*rc+31). ff_final's chunk-prefix starts at
//      c = 8*jb, dropping only exact +0.0f adds -> bit-identical scan.
//  (b) Q rows are block-uniform: read them from global with uniform
//      addresses (compiler scalarizes to s_load, scalar pipe) instead of
//      staging in LDS. Inner loop is pure v_fmac v,s,v -> removes the
//      ds_read_b128 bottleneck (was 6144 LDS cyc vs 4096 VALU cyc per wave).
//      No LDS, no barrier -> 4 waves/SIMD occupancy.
// ---------------------------------------------------------------------------
__global__ __launch_bounds__(256, 4) void ff_partial(const float* __restrict__ q0k0,
                                                     float* __restrict__ part) {
  const int rc = blockIdx.x;
  const int jb = blockIdx.y;
  if (rc < (jb << 3)) return;              // no r in chunk with r > j
  const int j = jb * 256 + threadIdx.x;

  float kk[64];
#pragma unroll
  for (int d4 = 0; d4 < 16; ++d4) {
    const fx4 kv = *(const fx4*)&q0k0[(size_t)j * 128 + 64 + d4 * 4];
    kk[d4 * 4 + 0] = kv.x; kk[d4 * 4 + 1] = kv.y;
    kk[d4 * 4 + 2] = kv.z; kk[d4 * 4 + 3] = kv.w;
  }

  float acc = 0.f;
  for (int rr = 0; rr < 32; ++rr) {
    const int r = rc * 32 + rr;
    const float* __restrict__ Qr = q0k0 + (size_t)r * 128;  // uniform -> s_load
    float d0 = 0.f, d1 = 0.f, d2 = 0.f, d3 = 0.f;
#pragma unroll
    for (int t4 = 0; t4 < 16; ++t4) {
      d0 = __builtin_fmaf(Qr[t4 * 4 + 0], kk[t4 * 4 + 0], d0);
      d1 = __builtin_fmaf(Qr[t4 * 4 + 1], kk[t4 * 4 + 1], d1);
      d2 = __builtin_fmaf(Qr[t4 * 4 + 2], kk[t4 * 4 + 2], d2);
      d3 = __builtin_fmaf(Qr[t4 * 4 + 3], kk[t4 * 4 + 3], d3);
    }
    const float s = ((d0 + d1) + (d2 + d3)) * 0.125f;
    if (r > j && j != 0 && s > 0.f) acc += s;
  }
  part[(size_t)rc * T + j] = acc;
}

__global__ __launch_bounds__(256, 4) void ff_final(const float* __restrict__ q0k0,
                                                   const float* __restrict__ part,
                                                   float* __restrict__ FF) {
  const int rc = blockIdx.x;
  const int jb = blockIdx.y;
  if (rc < (jb << 3)) return;              // no needed FF cell in this block
  const int j = jb * 256 + threadIdx.x;

  float kk[64];
#pragma unroll
  for (int d4 = 0; d4 < 16; ++d4) {
    const fx4 kv = *(const fx4*)&q0k0[(size_t)j * 128 + 64 + d4 * 4];
    kk[d4 * 4 + 0] = kv.x; kk[d4 * 4 + 1] = kv.y;
    kk[d4 * 4 + 2] = kv.z; kk[d4 * 4 + 3] = kv.w;
  }

  // exclusive prefix over chunks; chunks c < 8*jb are exactly 0 for all
  // j >= 256*jb (max row 32c+31 < 256*jb <= j) and were never written.
  float acc = 0.f;
  for (int c = (jb << 3); c < rc; ++c) acc += part[(size_t)c * T + j];

  for (int rr = 0; rr < 32; ++rr) {
    const int r = rc * 32 + rr;
    FF[(size_t)r * T + j] = acc;
    const float* __restrict__ Qr = q0k0 + (size_t)r * 128;  // uniform -> s_load
    float d0 = 0.f, d1 = 0.f, d2 = 0.f, d3 = 0.f;
#pragma unroll
    for (int t4 = 0; t4 < 16; ++t4) {
      d0 = __builtin_fmaf(Qr[t4 * 4 + 0], kk[t4 * 4 + 0], d0);
      d1 = __builtin_fmaf(Qr[t4 * 4 + 1], kk[t4 * 4 + 1], d1);
      d2 = __builtin_fmaf(Qr[t4 * 4 + 2], kk[t4 * 4 + 2], d2);
      d3 = __builtin_fmaf(Qr[t4 * 4 + 3], kk[t4 * 4 + 3], d3);
    }
    const float s = ((d0 + d1) + (d2 + d3)) * 0.125f;
    if (r > j && j != 0 && s > 0.f) acc += s;
  }
}

// ---------------------------------------------------------------------------
// MFMA flash attention (HW-verified round 12: ones-MFMA row sums, fixed-max
// softmax M=8, 768-block exact-balance j-split, K/V LDS dbuf, 1 barrier/tile).
// Unchanged this round.
// ---------------------------------------------------------------------------
__global__ __launch_bounds__(256) void attn_mfma(const __bf16* __restrict__ qkv,
                                                 const float* __restrict__ FF,
                                                 __bf16* __restrict__ y1,
                                                 float* __restrict__ Opart) {
  constexpr int LS = 72;
  constexpr int HALF = 64 * LS;
  __shared__ __bf16 Ks[2 * HALF];
  __shared__ __bf16 VsT[2 * HALF];
  __shared__ __bf16 Ps[HALF];
  const int id = blockIdx.x;
  const int h = id & 15;
  const int z = id >> 4;  // 0..47
  int qt, jt0, jt1, half;
  bool full;
  if (z < 16) {
    qt = z; jt0 = 0; jt1 = qt + 1; half = 0; full = true;
  } else {
    const int k = (z - 16) & 15;
    qt = 31 - k;
    half = (z >= 32);
    const int ha = (qt + 2) >> 1;
    jt0 = half ? ha : 0;
    jt1 = half ? qt + 1 : ha;
    full = false;
  }
  const int i0 = qt * 64;
  const int tid = threadIdx.x;
  const int wave = tid >> 6, lane = tid & 63;
  const int l15 = lane & 15, quad = lane >> 4;
  const int sr = tid >> 2, sc = (tid & 3) * 16;
  const int vr = lane, vc = wave * 16;
  const int qoff = h * HD, koff = CE + h * HD, voff = 2 * CE + h * HD;
  const int ffrow0 = i0 + wave * 16 + quad * 4;

  bfx8 aq0, aq1, ones8;
#pragma unroll
  for (int e = 0; e < 8; ++e) ones8[e] = (__bf16)1.f;
  {
    const bfx8 q0r = *(const bfx8*)&qkv[(size_t)(i0 + wave * 16 + l15) * QKVC + qoff + quad * 8];
    const bfx8 q1r = *(const bfx8*)&qkv[(size_t)(i0 + wave * 16 + l15) * QKVC + qoff + 32 + quad * 8];
#pragma unroll
    for (int e = 0; e < 8; ++e) aq0[e] = (__bf16)((float)q0r[e] * 0.125f);
#pragma unroll
    for (int e = 0; e < 8; ++e) aq1[e] = (__bf16)((float)q1r[e] * 0.125f);
  }

  f32x4 accO[4], accO5;
#pragma unroll
  for (int d = 0; d < 4; ++d) accO[d] = (f32x4){0.f, 0.f, 0.f, 0.f};
  accO5 = (f32x4){0.f, 0.f, 0.f, 0.f};

  u16x8 kpre0, kpre1;
  unsigned short vpre[16];
  float ffpre[4][4];
  {
    const int j0 = jt0 * 64;
    kpre0 = *(const u16x8*)&qkv[(size_t)(j0 + sr) * QKVC + koff + sc];
    kpre1 = *(const u16x8*)&qkv[(size_t)(j0 + sr) * QKVC + koff + sc + 8];
#pragma unroll
    for (int e = 0; e < 16; ++e)
      vpre[e] = ((const unsigned short*)qkv)[(size_t)(j0 + vc + e) * QKVC + voff + vr];
#pragma unroll
    for (int r = 0; r < 4; ++r)
#pragma unroll
      for (int c = 0; c < 4; ++c)
        ffpre[r][c] = FF[(size_t)(ffrow0 + r) * T + j0 + l15 + 16 * c];
  }

  for (int jt = jt0; jt < jt1; ++jt) {
    const int buf = (jt & 1) * HALF;
    {
      *(u16x8*)&Ks[buf + sr * LS + sc]     = kpre0;
      *(u16x8*)&Ks[buf + sr * LS + sc + 8] = kpre1;
      *(u16x8*)&VsT[buf + vr * LS + vc]     = *(u16x8*)&vpre[0];
      *(u16x8*)&VsT[buf + vr * LS + vc + 8] = *(u16x8*)&vpre[8];
    }

    float ffcur[4][4];
#pragma unroll
    for (int r = 0; r < 4; ++r)
#pragma unroll
      for (int c = 0; c < 4; ++c) ffcur[r][c] = ffpre[r][c];

    if (jt + 1 < jt1) {
      const int j0n = (jt + 1) * 64;
      kpre0 = *(const u16x8*)&qkv[(size_t)(j0n + sr) * QKVC + koff + sc];
      kpre1 = *(const u16x8*)&qkv[(size_t)(j0n + sr) * QKVC + koff + sc + 8];
#pragma unroll
      for (int e = 0; e < 16; ++e)
        vpre[e] = ((const unsigned short*)qkv)[(size_t)(j0n + vc + e) * QKVC + voff + vr];
#pragma unroll
      for (int r = 0; r < 4; ++r)
#pragma unroll
        for (int c = 0; c < 4; ++c)
          ffpre[r][c] = FF[(size_t)(ffrow0 + r) * T + j0n + l15 + 16 * c];
    }

    __syncthreads();

    f32x4 accS[4];
#pragma unroll
    for (int nb = 0; nb < 4; ++nb) accS[nb] = (f32x4){0.f, 0.f, 0.f, 0.f};
#pragma unroll
    for (int nb = 0; nb < 4; ++nb) {
      const bfx8 kb0 = *(const bfx8*)&Ks[buf + (nb * 16 + l15) * LS + quad * 8];
      const bfx8 kb1 = *(const bfx8*)&Ks[buf + (nb * 16 + l15) * LS + 32 + quad * 8];
      accS[nb] = __builtin_amdgcn_mfma_f32_16x16x32_bf16(aq0, kb0, accS[nb], 0, 0, 0);
      accS[nb] = __builtin_amdgcn_mfma_f32_16x16x32_bf16(aq1, kb1, accS[nb], 0, 0, 0);
    }

#pragma unroll
    for (int r = 0; r < 4; ++r) {
      const int row = wave * 16 + quad * 4 + r;
      float s0 = accS[0][r] - ffcur[r][0];
      float s1 = accS[1][r] - ffcur[r][1];
      float s2 = accS[2][r] - ffcur[r][2];
      float s3 = accS[3][r] - ffcur[r][3];
      if (jt == qt) {
        if (l15      > row) s0 = -1e30f;
        if (l15 + 16 > row) s1 = -1e30f;
        if (l15 + 32 > row) s2 = -1e30f;
        if (l15 + 48 > row) s3 = -1e30f;
      }
      Ps[row * LS + l15]      = (__bf16)__expf(s0 - 8.f);
      Ps[row * LS + l15 + 16] = (__bf16)__expf(s1 - 8.f);
      Ps[row * LS + l15 + 32] = (__bf16)__expf(s2 - 8.f);
      Ps[row * LS + l15 + 48] = (__bf16)__expf(s3 - 8.f);
    }

    const bfx8 ap0 = *(const bfx8*)&Ps[(wave * 16 + l15) * LS + quad * 8];
    const bfx8 ap1 = *(const bfx8*)&Ps[(wave * 16 + l15) * LS + 32 + quad * 8];
#pragma unroll
    for (int db = 0; db < 4; ++db) {
      const bfx8 vb0 = *(const bfx8*)&VsT[buf + (db * 16 + l15) * LS + quad * 8];
      const bfx8 vb1 = *(const bfx8*)&VsT[buf + (db * 16 + l15) * LS + 32 + quad * 8];
      accO[db] = __builtin_amdgcn_mfma_f32_16x16x32_bf16(ap0, vb0, accO[db], 0, 0, 0);
      accO[db] = __builtin_amdgcn_mfma_f32_16x16x32_bf16(ap1, vb1, accO[db], 0, 0, 0);
    }
    accO5 = __builtin_amdgcn_mfma_f32_16x16x32_bf16(ap0, ones8, accO5, 0, 0, 0);
    accO5 = __builtin_amdgcn_mfma_f32_16x16x32_bf16(ap1, ones8, accO5, 0, 0, 0);
  }

  if (full) {
#pragma unroll
    for (int r = 0; r < 4; ++r) {
      const float inv = 1.f / accO5[r];
      const int gi = i0 + wave * 16 + quad * 4 + r;
#pragma unroll
      for (int db = 0; db < 4; ++db)
        y1[(size_t)gi * CE + qoff + db * 16 + l15] = (__bf16)(accO[db][r] * inv);
    }
  } else {
    float* Ob = Opart + (size_t)(((qt - 16) * 2 + half) * 16 + h) * 4160;
#pragma unroll
    for (int r = 0; r < 4; ++r) {
      const int row = wave * 16 + quad * 4 + r;
#pragma unroll
      for (int db = 0; db < 4; ++db)
        Ob[row * 64 + db * 16 + l15] = accO[db][r];
      if (l15 == 0) Ob[4096 + row] = accO5[r];
    }
  }
}

// Combine the two halves for qt in [16,32): y1 = (Oa+Ob)/(la+lb).
__global__ __launch_bounds__(256) void attn_combine(const float* __restrict__ Opart,
                                                    __bf16* __restrict__ y1) {
  const int b = blockIdx.x;          // 256 = 16 q * 16 h
  const int h = b & 15, q = b >> 4;
  const int qt = 16 + q;
  const float* Oa = Opart + (size_t)((q * 2 + 0) * 16 + h) * 4160;
  const float* Ob = Opart + (size_t)((q * 2 + 1) * 16 + h) * 4160;
  const int row = threadIdx.x >> 2, c0 = (threadIdx.x & 3) * 16;
  const float inv = 1.f / (Oa[4096 + row] + Ob[4096 + row]);
  __bf16* dst = y1 + (size_t)(qt * 64 + row) * CE + h * HD + c0;
#pragma unroll
  for (int u = 0; u < 4; ++u) {
    const fx4 a = *(const fx4*)&Oa[row * 64 + c0 + u * 4];
    const fx4 bb = *(const fx4*)&Ob[row * 64 + c0 + u * 4];
    const fx4 v = (a + bb) * inv;
    dst[u * 4 + 0] = (__bf16)v.x; dst[u * 4 + 1] = (__bf16)v.y;
    dst[u * 4 + 2] = (__bf16)v.z; dst[u * 4 + 3] = (__bf16)v.w;
  }
}

// ---------------------------------------------------------------------------
extern "C" void kernel_launch(void* const* d_in, const int* in_sizes, int n_in,
                              void* d_out, int out_size, void* d_ws, size_t ws_size,
                              hipStream_t stream) {
  float* base  = (float*)d_ws;
  int*   flag  = (int*)d_ws;
  float* q0k0  = base + 64;                          // [T,128] fp32 (head-0 q|k)
  __bf16* qkvb = (__bf16*)(q0k0 + (size_t)T * 128);  // [T,QKVC] bf16
  float* R     = q0k0 + (size_t)T * 128 + (size_t)T * QKVC / 2;
  __bf16* xb  = (__bf16*)R;                          // flag=1 conv buffers ...
  __bf16* Wab = (__bf16*)(R + 1048576);
  __bf16* bab = (__bf16*)(R + 2621440);
  float*  FF   = R;                                  // [T,T] fp32 (over conv bufs)
  float*  part = R + 4194304;                        // [64,T] fp32
  __bf16* y1   = (__bf16*)(R + 4325376);             // [T,CE] bf16
  __bf16* Wpb  = (__bf16*)(R + 5373952);             // [CE,CE] bf16
  __bf16* bpb  = (__bf16*)(R + 5898240);             // [CE] bf16
  float*  Opart = R + 5898752;                       // 512 * 4160 fp32 (8.5 MB)

  sniff_kernel<<<1, 64, 0, stream>>>(d_in[0], flag);

  conv_all<<<CONV_BLOCKS, 256, 0, stream>>>(
      d_in[0], d_in[1], d_in[2], d_in[3], d_in[4], xb, Wab, bab, Wpb, bpb, flag);

  // 1) qkv = x @ W_attn^T + b_attn  -> bf16 qkvb + fp32 q0k0 side-store
  //    (64x128 tiles: 768 blocks = 3/CU balanced)
  gemm_mfma_nt<QKVC, CE, 2><<<dim3(QKVC / 128, T / 64), 256, 0, stream>>>(
      xb, d_in[0], Wab, d_in[1], bab, d_in[2], qkvb, q0k0, flag);

  // 2) FF decay cumsum, 2-phase (triangular block skip + scalar-Q, no LDS)
  ff_partial<<<dim3(64, 8), 256, 0, stream>>>(q0k0, part);
  ff_final<<<dim3(64, 8), 256, 0, stream>>>(q0k0, part, FF);

  // 3) MFMA flash attention (768 exact-balance blocks) -> y1 + partials
  attn_mfma<<<dim3(768), 256, 0, stream>>>(qkvb, FF, y1, Opart);
  attn_combine<<<dim3(256), 256, 0, stream>>>(Opart, y1);

  // 4) out = y1 @ W_proj^T + b_proj  (64x128 tiles: 256 blocks = all CUs)
  gemm_mfma_nt<CE, CE, 1><<<dim3(CE / 128, T / 64), 256, 0, stream>>>(
      y1, y1, Wpb, d_in[3], bpb, d_in[4], d_out, nullptr, flag);
}